// Round 4
// baseline (357.571 us; speedup 1.0000x reference)
//
#include <hip/hip_runtime.h>

#define IN_CH   128
#define D_OUT   128   // OUT_CH*HEADS
#define HEADS   4
#define N_TYPES 4
#define N_CONF  5
#define DCOLS   192   // 128 xt cols + 48 score cols (40 real + 8 pad)
#define SSTRIDE 24    // si/sj per-row stride: h*6+q (q<5 used)

typedef __attribute__((ext_vector_type(8))) short bf16x8;   // 8 bf16 (4 VGPRs)
typedef __attribute__((ext_vector_type(4))) float f32x4;

__device__ inline unsigned short bf16_rne(float f) {
    unsigned u = __float_as_uint(f);
    u += 0x7fff + ((u >> 16) & 1);
    return (unsigned short)(u >> 16);
}
// hi/lo split: f ~= hi + lo with ~2^-16 relative residual
__device__ inline void split_hl(float f, short& h, short& l) {
    unsigned u = __float_as_uint(f);
    h = (short)(u >> 16);
    float r = f - __uint_as_float(u & 0xffff0000u);   // exact
    l = (short)(__float_as_uint(r) >> 16);
}

// ---------------------------------------------------------------------------
// k_matt: M[t][k][col] = sum_{d'<32} W[t][k][32h+d'] * attv[q][h][fb*32+d']
//         col = fb*24 + h*6 + q  (q==5 -> 0 padding)
// ---------------------------------------------------------------------------
__global__ __launch_bounds__(256) void k_matt(const float* __restrict__ W,
                                              const float* __restrict__ attv,
                                              float* __restrict__ M) {
    const int g = blockIdx.x * 256 + threadIdx.x;   // 4*128*48
    if (g >= N_TYPES * 128 * 48) return;
    const int col = g % 48;
    const int k   = (g / 48) % 128;
    const int t   = g / (48 * 128);
    const int fb  = col / 24;
    const int rem = col % 24;
    const int h   = rem / 6;
    const int q   = rem % 6;
    float acc = 0.f;
    if (q < N_CONF) {
        const float* wr = W + ((size_t)t * 128 + k) * 128 + 32 * h;
        const float* ar = attv + ((size_t)q * HEADS + h) * 64 + fb * 32;
#pragma unroll
        for (int d = 0; d < 32; d++) acc += wr[d] * ar[d];
    }
    M[g] = acc;
}

// ---------------------------------------------------------------------------
// k_wprep: Wth/Wtl[t][dcol][k] = hi/lo bf16 of B'[t][k][dcol]
// ---------------------------------------------------------------------------
__global__ __launch_bounds__(256) void k_wprep(const float* __restrict__ W,
                                               const float* __restrict__ M,
                                               short* __restrict__ Wth,
                                               short* __restrict__ Wtl) {
    const int g = blockIdx.x * 256 + threadIdx.x;   // 4*128*192, dcol fastest
    if (g >= N_TYPES * 128 * DCOLS) return;
    const int dcol = g % DCOLS;
    const int k    = (g / DCOLS) % 128;
    const int t    = g / (DCOLS * 128);
    float v = 0.f;
    if (dcol < 128)      v = W[((size_t)t * 128 + k) * 128 + dcol];
    else if (dcol < 176) v = M[((size_t)t * 128 + k) * 48 + (dcol - 128)];
    short h, l; split_hl(v, h, l);
    const size_t o = ((size_t)t * DCOLS + dcol) * 128 + k;
    Wth[o] = h; Wtl[o] = l;
}

// ---------------------------------------------------------------------------
// k_linear (v0, proven 70us): bf16 hi/lo MFMA GEMM, [64 x 128] x [128 x 192].
// Grid (nblocks, N_TYPES): 12 waves/CU of TLP hides stage+B-load latency.
// ---------------------------------------------------------------------------
__global__ __launch_bounds__(256) void k_linear(const float* __restrict__ x,
                                                const short* __restrict__ Wth,
                                                const short* __restrict__ Wtl,
                                                short* __restrict__ xtb,
                                                float* __restrict__ si,
                                                float* __restrict__ sj,
                                                int N) {
    __shared__ __align__(16) char smem[34816];
    short* Xh = (short*)smem;             // 64*136 shorts
    short* Xl = (short*)(smem + 17408);   // 64*136 shorts

    const int tid   = threadIdx.x;
    const int nbase = blockIdx.x * 64;
    const int t     = blockIdx.y;

    // stage X tile -> hi/lo bf16
#pragma unroll
    for (int i = 0; i < 8; i++) {
        const int f   = tid + i * 256;       // 0..2047
        const int row = f >> 5;
        const int c4  = (f & 31) * 4;
        float4 v = make_float4(0.f, 0.f, 0.f, 0.f);
        const int ng = nbase + row;
        if (ng < N) v = *(const float4*)(x + (size_t)ng * IN_CH + c4);
        short4 h4, l4;
        split_hl(v.x, h4.x, l4.x);
        split_hl(v.y, h4.y, l4.y);
        split_hl(v.z, h4.z, l4.z);
        split_hl(v.w, h4.w, l4.w);
        *(short4*)(Xh + row * 136 + c4) = h4;
        *(short4*)(Xl + row * 136 + c4) = l4;
    }
    __syncthreads();

    const int w    = tid >> 6;
    const int lane = tid & 63;
    const int n16  = lane & 15;
    const int quad = lane >> 4;

    f32x4 acc[3][4];
#pragma unroll
    for (int tt = 0; tt < 3; tt++)
#pragma unroll
        for (int mt = 0; mt < 4; mt++) acc[tt][mt] = (f32x4){0.f, 0.f, 0.f, 0.f};

#pragma unroll
    for (int kc = 0; kc < 4; kc++) {
        bf16x8 Ah[4], Al[4];
#pragma unroll
        for (int mt = 0; mt < 4; mt++) {
            const int r = (mt * 16 + n16) * 136 + kc * 32 + quad * 8;
            Ah[mt] = *(const bf16x8*)(Xh + r);
            Al[mt] = *(const bf16x8*)(Xl + r);
        }
#pragma unroll
        for (int tt = 0; tt < 3; tt++) {
            const int dcol = (w * 3 + tt) * 16 + n16;
            const size_t off = ((size_t)t * DCOLS + dcol) * 128 + kc * 32 + quad * 8;
            const bf16x8 Bh = *(const bf16x8*)(Wth + off);
            const bf16x8 Bl = *(const bf16x8*)(Wtl + off);
#pragma unroll
            for (int mt = 0; mt < 4; mt++) {
                acc[tt][mt] = __builtin_amdgcn_mfma_f32_16x16x32_bf16(Ah[mt], Bh, acc[tt][mt], 0, 0, 0);
                acc[tt][mt] = __builtin_amdgcn_mfma_f32_16x16x32_bf16(Ah[mt], Bl, acc[tt][mt], 0, 0, 0);
                acc[tt][mt] = __builtin_amdgcn_mfma_f32_16x16x32_bf16(Al[mt], Bh, acc[tt][mt], 0, 0, 0);
            }
        }
    }

    // -------- stage epilogue through LDS (reuse smem) --------
    __syncthreads();
    unsigned short* SB = (unsigned short*)smem;     // [64][128], 16B-block swizzled
    float*          SS = (float*)(smem + 16384);    // [64][48]

#pragma unroll
    for (int tt = 0; tt < 3; tt++) {
        const int dcol = (w * 3 + tt) * 16 + n16;
        if (dcol < 128) {
            const int blk = dcol >> 3;
#pragma unroll
            for (int mt = 0; mt < 4; mt++)
#pragma unroll
                for (int r = 0; r < 4; r++) {
                    const int nl = mt * 16 + quad * 4 + r;
                    SB[nl * 128 + (((blk ^ (nl & 15)) << 3) | (dcol & 7))] =
                        bf16_rne(acc[tt][mt][r]);
                }
        } else if (dcol < 176) {
            const int c = dcol - 128;   // 0..47: [si 0..23 | sj 0..23]
#pragma unroll
            for (int mt = 0; mt < 4; mt++)
#pragma unroll
                for (int r = 0; r < 4; r++) {
                    const int nl = mt * 16 + quad * 4 + r;
                    SS[nl * 48 + c] = acc[tt][mt][r];
                }
        }
    }
    __syncthreads();

    const size_t trow = (size_t)t * N;
    // xtb: 64 rows x 16 blocks of 16B, coalesced dwordx4 stores
#pragma unroll
    for (int it = 0; it < 4; it++) {
        const int task = tid + it * 256;        // 0..1023
        const int r    = task >> 4;
        const int blk  = task & 15;
        if (nbase + r < N) {
            const uint4 v = *(const uint4*)(SB + r * 128 + ((blk ^ (r & 15)) << 3));
            *(uint4*)(xtb + (trow + nbase + r) * (size_t)D_OUT + (blk << 3)) = v;
        }
    }
    // scores: 64 rows x 12 float4 pieces (6 si + 6 sj)
#pragma unroll
    for (int it = 0; it < 3; it++) {
        const int task = tid + it * 256;        // 0..767
        const int r    = task / 12;
        const int p    = task % 12;
        if (nbase + r < N) {
            const float4 v = *(const float4*)(SS + r * 48 + p * 4);
            float* dp = (p < 6) ? (si + (trow + nbase + r) * SSTRIDE + p * 4)
                                : (sj + (trow + nbase + r) * SSTRIDE + (p - 6) * 4);
            *(float4*)dp = v;
        }
    }
}

// ---------------------------------------------------------------------------
// CSR build over segments seg = dst*4 + type
// ---------------------------------------------------------------------------
__global__ __launch_bounds__(256) void k_hist(const int* __restrict__ dst,
                                              const int* __restrict__ et,
                                              int* __restrict__ counts, int E) {
    const int e = blockIdx.x * 256 + threadIdx.x;
    if (e < E) atomicAdd(&counts[dst[e] * 4 + et[e]], 1);
}

__global__ __launch_bounds__(256) void k_scan_part(const int* __restrict__ counts,
                                                   int* __restrict__ partial, int NS) {
    __shared__ int s[256];
    const int b = blockIdx.x, t = threadIdx.x;
    const int base = b * 1024 + t * 4;
    int sum = 0;
#pragma unroll
    for (int i = 0; i < 4; i++) if (base + i < NS) sum += counts[base + i];
    s[t] = sum; __syncthreads();
    for (int off = 128; off > 0; off >>= 1) {
        if (t < off) s[t] += s[t + off];
        __syncthreads();
    }
    if (t == 0) partial[b] = s[0];
}

__global__ __launch_bounds__(256) void k_scan_partials(int* __restrict__ partial, int nb) {
    __shared__ int s[256];
    const int t = threadIdx.x;
    int v = (t < nb) ? partial[t] : 0;
    s[t] = v; __syncthreads();
    for (int off = 1; off < 256; off <<= 1) {
        int x = (t >= off) ? s[t - off] : 0;
        __syncthreads();
        s[t] += x;
        __syncthreads();
    }
    if (t < nb) partial[t] = s[t] - v;   // exclusive
}

__global__ __launch_bounds__(256) void k_scan_chunk(const int* __restrict__ counts,
                                                    const int* __restrict__ partial,
                                                    int* __restrict__ offsets,
                                                    int* __restrict__ cursor, int NS) {
    __shared__ int s[256];
    const int b = blockIdx.x, t = threadIdx.x;
    const int base = b * 1024 + t * 4;
    int v[4]; int sum = 0;
#pragma unroll
    for (int i = 0; i < 4; i++) { v[i] = (base + i < NS) ? counts[base + i] : 0; sum += v[i]; }
    s[t] = sum; __syncthreads();
    for (int off = 1; off < 256; off <<= 1) {
        int x = (t >= off) ? s[t - off] : 0;
        __syncthreads();
        s[t] += x;
        __syncthreads();
    }
    int run = partial[b] + s[t] - sum;
#pragma unroll
    for (int i = 0; i < 4; i++) {
        const int idx = base + i;
        if (idx < NS) { offsets[idx] = run; cursor[idx] = run; run += v[i]; }
    }
}

// k_fill: only esrc (eseg eliminated — type derived from CSR walk)
__global__ __launch_bounds__(256) void k_fill(const int* __restrict__ src,
                                              const int* __restrict__ dst,
                                              const int* __restrict__ et,
                                              int* __restrict__ cursor,
                                              int* __restrict__ esrc, int E) {
    const int e = blockIdx.x * 256 + threadIdx.x;
    if (e < E) {
        const int seg = dst[e] * 4 + et[e];
        const int pos = atomicAdd(&cursor[seg], 1);
        esrc[pos] = src[e];
    }
}

// ---------------------------------------------------------------------------
// k_node v2: one wave per dst node; chunked esrc preload + WAVE-COOPERATIVE
// alpha precompute: at each 64-edge chunk, 4 rounds x (64 lanes = 16 edges x
// 4 heads) compute exp-weights into w0..w3; inner loop fetches its weight
// with one __shfl. Removes the 16x-redundant per-lane alpha recompute that
// made round-3's k_node VALU-bound (76% VALUBusy).
// ---------------------------------------------------------------------------
__global__ __launch_bounds__(256) void k_node(const short* __restrict__ xtb,
                                              const int* __restrict__ offsets,
                                              const int* __restrict__ counts,
                                              const int* __restrict__ esrc,
                                              const float* __restrict__ si,
                                              const float* __restrict__ sj,
                                              const float* __restrict__ cprobs,
                                              const float* __restrict__ imp,
                                              const float* __restrict__ bias,
                                              float* __restrict__ out,
                                              int N) {
    __shared__ float imp_s[N_TYPES];
    __shared__ float pk_s[N_CONF];
    if (threadIdx.x == 0) {
        float m = cprobs[0];
        for (int k = 1; k < N_CONF; k++) m = fmaxf(m, cprobs[k]);
        float ex[N_CONF], s = 0.f;
        for (int k = 0; k < N_CONF; k++) { ex[k] = __expf(cprobs[k] - m); s += ex[k]; }
        for (int k = 0; k < N_CONF; k++) pk_s[k] = ex[k] / s;
    }
    if (threadIdx.x < N_TYPES) imp_s[threadIdx.x] = imp[threadIdx.x];
    __syncthreads();

    float pk[N_CONF];
#pragma unroll
    for (int q = 0; q < N_CONF; q++) pk[q] = pk_s[q];

    const int node = blockIdx.x * 4 + (threadIdx.x >> 6);
    if (node >= N) return;
    const int lane = threadIdx.x & 63;
    const int quad = lane >> 4;   // inner loop: == head; precompute: head this lane computes
    const int esub = lane & 15;   // precompute: edge-within-16 this lane computes
    const size_t tstride = (size_t)N * D_OUT;

    const int o0 = offsets[node * 4];
    int c[N_TYPES];
#pragma unroll
    for (int t = 0; t < N_TYPES; t++) c[t] = counts[node * 4 + t];
    const int ndeg = c[0] + c[1] + c[2] + c[3];
    const int b0 = c[0];
    const int b1 = c[0] + c[1];
    const int b2 = b1 + c[2];

    int chunk = -1;
    int sv = 0;
    float w0 = 0.f, w1 = 0.f, w2 = 0.f, w3 = 0.f;   // per-16-edge weight regs
    float oacc0 = 0.f, oacc1 = 0.f;
    int k = 0;

#pragma unroll
    for (int t = 0; t < N_TYPES; t++) {
        const int cnt = c[t];
        if (cnt == 0) continue;

        float ax = 0.f, ay = 0.f, den = 0.f;
        const short* tbase = xtb + (size_t)t * tstride;
        for (int i = 0; i < cnt; i++, k++) {
            const int cc = k >> 6;
            if (cc != chunk) {                        // wave-uniform, once per 64 edges
                chunk = cc;
                const int rel = cc * 64 + lane;
                sv = esrc[(rel < ndeg) ? (o0 + rel) : o0];   // 1 coalesced load

                // cooperative alpha precompute: 4 rounds x (16 edges x 4 heads)
#pragma unroll
                for (int s = 0; s < 4; s++) {
                    const int e  = cc * 64 + s * 16 + esub;        // edge idx in node
                    const int sn = __shfl(sv, s * 16 + esub);      // its src (clamped ok)
                    const int te = (e >= b0) + (e >= b1) + (e >= b2);
                    const float* ipp = si + ((size_t)te * N + node) * SSTRIDE + quad * 6;
                    const float* jpp = sj + ((size_t)te * N + sn)   * SSTRIDE + quad * 6;
                    const float2 i01 = *(const float2*)(ipp);
                    const float2 i23 = *(const float2*)(ipp + 2);
                    const float  i4  = ipp[4];
                    const float2 j01 = *(const float2*)(jpp);
                    const float2 j23 = *(const float2*)(jpp + 2);
                    const float  j4  = jpp[4];
                    float alpha = 0.f;
                    float s0 = i01.x + j01.x; s0 = (s0 > 0.f) ? s0 : 0.2f * s0; alpha += s0 * pk[0];
                    float s1 = i01.y + j01.y; s1 = (s1 > 0.f) ? s1 : 0.2f * s1; alpha += s1 * pk[1];
                    float s2 = i23.x + j23.x; s2 = (s2 > 0.f) ? s2 : 0.2f * s2; alpha += s2 * pk[2];
                    float s3 = i23.y + j23.y; s3 = (s3 > 0.f) ? s3 : 0.2f * s3; alpha += s3 * pk[3];
                    float s4 = i4    + j4;    s4 = (s4 > 0.f) ? s4 : 0.2f * s4; alpha += s4 * pk[4];
                    const float ww = __expf(alpha);
                    if (s == 0) w0 = ww;
                    else if (s == 1) w1 = ww;
                    else if (s == 2) w2 = ww;
                    else w3 = ww;
                }
            }
            const int sn = __shfl(sv, k & 63);
            // select weight register (k is wave-uniform -> uniform selects)
            const float wsel = (k & 32) ? ((k & 16) ? w3 : w2)
                                        : ((k & 16) ? w1 : w0);
            const float w = __shfl(wsel, quad * 16 + (k & 15));

            const unsigned u = ((const unsigned*)(tbase + (size_t)sn * D_OUT))[lane];
            ax  += __uint_as_float(u << 16) * w;
            ay  += __uint_as_float(u & 0xffff0000u) * w;
            den += w;
        }
        const float f = imp_s[t] / den;
        oacc0 += ax * f;
        oacc1 += ay * f;
    }

    // self-loop (type 0 transform of own features) + bias, pure store
    const unsigned u0 = ((const unsigned*)(xtb + (size_t)node * D_OUT))[lane];
    const float2 bv = ((const float2*)bias)[lane];
    float2 ov;
    ov.x = __uint_as_float(u0 << 16)          + bv.x + oacc0;
    ov.y = __uint_as_float(u0 & 0xffff0000u)  + bv.y + oacc1;
    ((float2*)(out + (size_t)node * D_OUT))[lane] = ov;
}

// ---------------------------------------------------------------------------
extern "C" void kernel_launch(void* const* d_in, const int* in_sizes, int n_in,
                              void* d_out, int out_size, void* d_ws, size_t ws_size,
                              hipStream_t stream) {
    const float* x    = (const float*)d_in[0];
    const int*   ei   = (const int*)d_in[1];
    const int*   et   = (const int*)d_in[2];
    const float* W    = (const float*)d_in[3];
    const float* attv = (const float*)d_in[4];
    const float* cpr  = (const float*)d_in[5];
    const float* imp  = (const float*)d_in[6];
    const float* bias = (const float*)d_in[7];

    const int N = in_sizes[0] / IN_CH;
    const int E = in_sizes[2];
    const int* src = ei;        // edge_index[0]
    const int* dst = ei + E;    // edge_index[1]
    const int NS = N * N_TYPES;

    char* ws = (char*)d_ws;
    float* si      = (float*)ws;  ws += (size_t)N_TYPES * N * SSTRIDE * sizeof(float);
    float* sj      = (float*)ws;  ws += (size_t)N_TYPES * N * SSTRIDE * sizeof(float);
    float* M       = (float*)ws;  ws += (size_t)N_TYPES * 128 * 48 * sizeof(float);
    short* Wth     = (short*)ws;  ws += (size_t)N_TYPES * DCOLS * 128 * sizeof(short);
    short* Wtl     = (short*)ws;  ws += (size_t)N_TYPES * DCOLS * 128 * sizeof(short);
    short* xtb     = (short*)ws;  ws += (size_t)N_TYPES * N * D_OUT * sizeof(short);
    int*   counts  = (int*)ws;    ws += (size_t)NS * sizeof(int);
    int*   offsets = (int*)ws;    ws += (size_t)NS * sizeof(int);
    int*   cursor  = (int*)ws;    ws += (size_t)NS * sizeof(int);
    int*   partial = (int*)ws;    ws += 256 * sizeof(int);
    int*   esrc    = (int*)ws;    ws += (size_t)E * sizeof(int);
    float* out = (float*)d_out;

    hipMemsetAsync(counts, 0, (size_t)NS * sizeof(int), stream);

    k_matt<<<(N_TYPES * 128 * 48 + 255) / 256, 256, 0, stream>>>(W, attv, M);
    k_wprep<<<(N_TYPES * 128 * DCOLS + 255) / 256, 256, 0, stream>>>(W, M, Wth, Wtl);

    const int nblocks = (N + 63) / 64;
    k_linear<<<dim3(nblocks, N_TYPES), 256, 0, stream>>>(x, Wth, Wtl, xtb, si, sj, N);

    const int eb = (E + 255) / 256;
    const int nb = (NS + 1023) / 1024;
    k_hist<<<eb, 256, 0, stream>>>(dst, et, counts, E);
    k_scan_part<<<nb, 256, 0, stream>>>(counts, partial, NS);
    k_scan_partials<<<1, 256, 0, stream>>>(partial, nb);
    k_scan_chunk<<<nb, 256, 0, stream>>>(counts, partial, offsets, cursor, NS);
    k_fill<<<eb, 256, 0, stream>>>(src, dst, et, cursor, esrc, E);

    k_node<<<(N + 3) / 4, 256, 0, stream>>>(xtb, offsets, counts, esrc, si, sj, cpr, imp, bias, out, N);
}

// Round 5
// 326.389 us; speedup vs baseline: 1.0955x; 1.0955x over previous
//
#include <hip/hip_runtime.h>

#define IN_CH   128
#define D_OUT   128   // OUT_CH*HEADS
#define HEADS   4
#define N_TYPES 4
#define N_CONF  5
#define DCOLS   192   // 128 xt cols + 48 score cols (40 real + 8 pad)
#define SSTRIDE 24    // si/sj per-row stride: h*6+q (q<5 used)

typedef __attribute__((ext_vector_type(8))) short bf16x8;   // 8 bf16 (4 VGPRs)
typedef __attribute__((ext_vector_type(4))) float f32x4;

__device__ inline unsigned short bf16_rne(float f) {
    unsigned u = __float_as_uint(f);
    u += 0x7fff + ((u >> 16) & 1);
    return (unsigned short)(u >> 16);
}
// hi/lo split: f ~= hi + lo with ~2^-16 relative residual
__device__ inline void split_hl(float f, short& h, short& l) {
    unsigned u = __float_as_uint(f);
    h = (short)(u >> 16);
    float r = f - __uint_as_float(u & 0xffff0000u);   // exact
    l = (short)(__float_as_uint(r) >> 16);
}

// ---------------------------------------------------------------------------
// k_matt: M[t][k][col] = sum_{d'<32} W[t][k][32h+d'] * attv[q][h][fb*32+d']
//         col = fb*24 + h*6 + q  (q==5 -> 0 padding)
// ---------------------------------------------------------------------------
__global__ __launch_bounds__(256) void k_matt(const float* __restrict__ W,
                                              const float* __restrict__ attv,
                                              float* __restrict__ M) {
    const int g = blockIdx.x * 256 + threadIdx.x;   // 4*128*48
    if (g >= N_TYPES * 128 * 48) return;
    const int col = g % 48;
    const int k   = (g / 48) % 128;
    const int t   = g / (48 * 128);
    const int fb  = col / 24;
    const int rem = col % 24;
    const int h   = rem / 6;
    const int q   = rem % 6;
    float acc = 0.f;
    if (q < N_CONF) {
        const float* wr = W + ((size_t)t * 128 + k) * 128 + 32 * h;
        const float* ar = attv + ((size_t)q * HEADS + h) * 64 + fb * 32;
#pragma unroll
        for (int d = 0; d < 32; d++) acc += wr[d] * ar[d];
    }
    M[g] = acc;
}

// ---------------------------------------------------------------------------
// k_wprep: Wth/Wtl[t][dcol][k] = hi/lo bf16 of B'[t][k][dcol]
// ---------------------------------------------------------------------------
__global__ __launch_bounds__(256) void k_wprep(const float* __restrict__ W,
                                               const float* __restrict__ M,
                                               short* __restrict__ Wth,
                                               short* __restrict__ Wtl) {
    const int g = blockIdx.x * 256 + threadIdx.x;   // 4*128*192, dcol fastest
    if (g >= N_TYPES * 128 * DCOLS) return;
    const int dcol = g % DCOLS;
    const int k    = (g / DCOLS) % 128;
    const int t    = g / (DCOLS * 128);
    float v = 0.f;
    if (dcol < 128)      v = W[((size_t)t * 128 + k) * 128 + dcol];
    else if (dcol < 176) v = M[((size_t)t * 128 + k) * 48 + (dcol - 128)];
    short h, l; split_hl(v, h, l);
    const size_t o = ((size_t)t * DCOLS + dcol) * 128 + k;
    Wth[o] = h; Wtl[o] = l;
}

// ---------------------------------------------------------------------------
// k_linear (v0, proven 70us): bf16 hi/lo MFMA GEMM, [64 x 128] x [128 x 192].
// Grid (nblocks, N_TYPES): 12 waves/CU of TLP hides stage+B-load latency.
// ---------------------------------------------------------------------------
__global__ __launch_bounds__(256) void k_linear(const float* __restrict__ x,
                                                const short* __restrict__ Wth,
                                                const short* __restrict__ Wtl,
                                                short* __restrict__ xtb,
                                                float* __restrict__ si,
                                                float* __restrict__ sj,
                                                int N) {
    __shared__ __align__(16) char smem[34816];
    short* Xh = (short*)smem;             // 64*136 shorts
    short* Xl = (short*)(smem + 17408);   // 64*136 shorts

    const int tid   = threadIdx.x;
    const int nbase = blockIdx.x * 64;
    const int t     = blockIdx.y;

    // stage X tile -> hi/lo bf16
#pragma unroll
    for (int i = 0; i < 8; i++) {
        const int f   = tid + i * 256;       // 0..2047
        const int row = f >> 5;
        const int c4  = (f & 31) * 4;
        float4 v = make_float4(0.f, 0.f, 0.f, 0.f);
        const int ng = nbase + row;
        if (ng < N) v = *(const float4*)(x + (size_t)ng * IN_CH + c4);
        short4 h4, l4;
        split_hl(v.x, h4.x, l4.x);
        split_hl(v.y, h4.y, l4.y);
        split_hl(v.z, h4.z, l4.z);
        split_hl(v.w, h4.w, l4.w);
        *(short4*)(Xh + row * 136 + c4) = h4;
        *(short4*)(Xl + row * 136 + c4) = l4;
    }
    __syncthreads();

    const int w    = tid >> 6;
    const int lane = tid & 63;
    const int n16  = lane & 15;
    const int quad = lane >> 4;

    f32x4 acc[3][4];
#pragma unroll
    for (int tt = 0; tt < 3; tt++)
#pragma unroll
        for (int mt = 0; mt < 4; mt++) acc[tt][mt] = (f32x4){0.f, 0.f, 0.f, 0.f};

#pragma unroll
    for (int kc = 0; kc < 4; kc++) {
        bf16x8 Ah[4], Al[4];
#pragma unroll
        for (int mt = 0; mt < 4; mt++) {
            const int r = (mt * 16 + n16) * 136 + kc * 32 + quad * 8;
            Ah[mt] = *(const bf16x8*)(Xh + r);
            Al[mt] = *(const bf16x8*)(Xl + r);
        }
#pragma unroll
        for (int tt = 0; tt < 3; tt++) {
            const int dcol = (w * 3 + tt) * 16 + n16;
            const size_t off = ((size_t)t * DCOLS + dcol) * 128 + kc * 32 + quad * 8;
            const bf16x8 Bh = *(const bf16x8*)(Wth + off);
            const bf16x8 Bl = *(const bf16x8*)(Wtl + off);
#pragma unroll
            for (int mt = 0; mt < 4; mt++) {
                acc[tt][mt] = __builtin_amdgcn_mfma_f32_16x16x32_bf16(Ah[mt], Bh, acc[tt][mt], 0, 0, 0);
                acc[tt][mt] = __builtin_amdgcn_mfma_f32_16x16x32_bf16(Ah[mt], Bl, acc[tt][mt], 0, 0, 0);
                acc[tt][mt] = __builtin_amdgcn_mfma_f32_16x16x32_bf16(Al[mt], Bh, acc[tt][mt], 0, 0, 0);
            }
        }
    }

    // -------- stage epilogue through LDS (reuse smem) --------
    __syncthreads();
    unsigned short* SB = (unsigned short*)smem;     // [64][128], 16B-block swizzled
    float*          SS = (float*)(smem + 16384);    // [64][48]

#pragma unroll
    for (int tt = 0; tt < 3; tt++) {
        const int dcol = (w * 3 + tt) * 16 + n16;
        if (dcol < 128) {
            const int blk = dcol >> 3;
#pragma unroll
            for (int mt = 0; mt < 4; mt++)
#pragma unroll
                for (int r = 0; r < 4; r++) {
                    const int nl = mt * 16 + quad * 4 + r;
                    SB[nl * 128 + (((blk ^ (nl & 15)) << 3) | (dcol & 7))] =
                        bf16_rne(acc[tt][mt][r]);
                }
        } else if (dcol < 176) {
            const int c = dcol - 128;   // 0..47: [si 0..23 | sj 0..23]
#pragma unroll
            for (int mt = 0; mt < 4; mt++)
#pragma unroll
                for (int r = 0; r < 4; r++) {
                    const int nl = mt * 16 + quad * 4 + r;
                    SS[nl * 48 + c] = acc[tt][mt][r];
                }
        }
    }
    __syncthreads();

    const size_t trow = (size_t)t * N;
    // xtb: 64 rows x 16 blocks of 16B, coalesced dwordx4 stores
#pragma unroll
    for (int it = 0; it < 4; it++) {
        const int task = tid + it * 256;        // 0..1023
        const int r    = task >> 4;
        const int blk  = task & 15;
        if (nbase + r < N) {
            const uint4 v = *(const uint4*)(SB + r * 128 + ((blk ^ (r & 15)) << 3));
            *(uint4*)(xtb + (trow + nbase + r) * (size_t)D_OUT + (blk << 3)) = v;
        }
    }
    // scores: 64 rows x 12 float4 pieces (6 si + 6 sj)
#pragma unroll
    for (int it = 0; it < 3; it++) {
        const int task = tid + it * 256;        // 0..767
        const int r    = task / 12;
        const int p    = task % 12;
        if (nbase + r < N) {
            const float4 v = *(const float4*)(SS + r * 48 + p * 4);
            float* dp = (p < 6) ? (si + (trow + nbase + r) * SSTRIDE + p * 4)
                                : (sj + (trow + nbase + r) * SSTRIDE + (p - 6) * 4);
            *(float4*)dp = v;
        }
    }
}

// ---------------------------------------------------------------------------
// CSR build over segments seg = dst*4 + type
// ---------------------------------------------------------------------------
__global__ __launch_bounds__(256) void k_hist(const int* __restrict__ dst,
                                              const int* __restrict__ et,
                                              int* __restrict__ counts, int E) {
    const int e = blockIdx.x * 256 + threadIdx.x;
    if (e < E) atomicAdd(&counts[dst[e] * 4 + et[e]], 1);
}

__global__ __launch_bounds__(256) void k_scan_part(const int* __restrict__ counts,
                                                   int* __restrict__ partial, int NS) {
    __shared__ int s[256];
    const int b = blockIdx.x, t = threadIdx.x;
    const int base = b * 1024 + t * 4;
    int sum = 0;
#pragma unroll
    for (int i = 0; i < 4; i++) if (base + i < NS) sum += counts[base + i];
    s[t] = sum; __syncthreads();
    for (int off = 128; off > 0; off >>= 1) {
        if (t < off) s[t] += s[t + off];
        __syncthreads();
    }
    if (t == 0) partial[b] = s[0];
}

__global__ __launch_bounds__(256) void k_scan_partials(int* __restrict__ partial, int nb) {
    __shared__ int s[256];
    const int t = threadIdx.x;
    int v = (t < nb) ? partial[t] : 0;
    s[t] = v; __syncthreads();
    for (int off = 1; off < 256; off <<= 1) {
        int x = (t >= off) ? s[t - off] : 0;
        __syncthreads();
        s[t] += x;
        __syncthreads();
    }
    if (t < nb) partial[t] = s[t] - v;   // exclusive
}

__global__ __launch_bounds__(256) void k_scan_chunk(const int* __restrict__ counts,
                                                    const int* __restrict__ partial,
                                                    int* __restrict__ offsets,
                                                    int* __restrict__ cursor, int NS) {
    __shared__ int s[256];
    const int b = blockIdx.x, t = threadIdx.x;
    const int base = b * 1024 + t * 4;
    int v[4]; int sum = 0;
#pragma unroll
    for (int i = 0; i < 4; i++) { v[i] = (base + i < NS) ? counts[base + i] : 0; sum += v[i]; }
    s[t] = sum; __syncthreads();
    for (int off = 1; off < 256; off <<= 1) {
        int x = (t >= off) ? s[t - off] : 0;
        __syncthreads();
        s[t] += x;
        __syncthreads();
    }
    int run = partial[b] + s[t] - sum;
#pragma unroll
    for (int i = 0; i < 4; i++) {
        const int idx = base + i;
        if (idx < NS) { offsets[idx] = run; cursor[idx] = run; run += v[i]; }
    }
}

// k_fill: only esrc (eseg eliminated — type derived from CSR walk)
__global__ __launch_bounds__(256) void k_fill(const int* __restrict__ src,
                                              const int* __restrict__ dst,
                                              const int* __restrict__ et,
                                              int* __restrict__ cursor,
                                              int* __restrict__ esrc, int E) {
    const int e = blockIdx.x * 256 + threadIdx.x;
    if (e < E) {
        const int seg = dst[e] * 4 + et[e];
        const int pos = atomicAdd(&cursor[seg], 1);
        esrc[pos] = src[e];
    }
}

// ---------------------------------------------------------------------------
// k_node v3: one wave per dst node; chunked esrc preload.
// Cooperative alpha precompute, fixed vs v2: (a) rounds clamped to
// ceil(valid/16) (usually 1 for avg deg 16), clamped lanes predicated off;
// (b) weights parked in per-wave LDS table -> inner loop does ONE broadcast
// ds_read (16 lanes/quad same addr) instead of shfl+cndmask chains.
// Inner loop = 1 shfl(sn) + 1 LDS read + 1 gather + 5 VALU, as in the
// proven round-3 loop minus the redundant alpha math.
// ---------------------------------------------------------------------------
__global__ __launch_bounds__(256) void k_node(const short* __restrict__ xtb,
                                              const int* __restrict__ offsets,
                                              const int* __restrict__ counts,
                                              const int* __restrict__ esrc,
                                              const float* __restrict__ si,
                                              const float* __restrict__ sj,
                                              const float* __restrict__ cprobs,
                                              const float* __restrict__ imp,
                                              const float* __restrict__ bias,
                                              float* __restrict__ out,
                                              int N) {
    __shared__ float imp_s[N_TYPES];
    __shared__ float pk_s[N_CONF];
    __shared__ float wlds[4][64 * HEADS];   // per-wave weight table [edge][head]
    if (threadIdx.x == 0) {
        float m = cprobs[0];
        for (int k = 1; k < N_CONF; k++) m = fmaxf(m, cprobs[k]);
        float ex[N_CONF], s = 0.f;
        for (int k = 0; k < N_CONF; k++) { ex[k] = __expf(cprobs[k] - m); s += ex[k]; }
        for (int k = 0; k < N_CONF; k++) pk_s[k] = ex[k] / s;
    }
    if (threadIdx.x < N_TYPES) imp_s[threadIdx.x] = imp[threadIdx.x];
    __syncthreads();

    float pk[N_CONF];
#pragma unroll
    for (int q = 0; q < N_CONF; q++) pk[q] = pk_s[q];

    const int wid  = threadIdx.x >> 6;
    const int node = blockIdx.x * 4 + wid;
    if (node >= N) return;
    const int lane = threadIdx.x & 63;
    const int quad = lane >> 4;   // inner loop: == head; precompute: head this lane computes
    const int esub = lane & 15;   // precompute: edge-within-16 this lane computes
    const size_t tstride = (size_t)N * D_OUT;
    float* wrow = wlds[wid];

    const int o0 = offsets[node * 4];
    int c[N_TYPES];
#pragma unroll
    for (int t = 0; t < N_TYPES; t++) c[t] = counts[node * 4 + t];
    const int ndeg = c[0] + c[1] + c[2] + c[3];
    const int b0 = c[0];
    const int b1 = c[0] + c[1];
    const int b2 = b1 + c[2];

    int chunk = -1;
    int sv = 0;
    float oacc0 = 0.f, oacc1 = 0.f;
    int k = 0;

#pragma unroll
    for (int t = 0; t < N_TYPES; t++) {
        const int cnt = c[t];
        if (cnt == 0) continue;

        float ax = 0.f, ay = 0.f, den = 0.f;
        const short* tbase = xtb + (size_t)t * tstride;
        for (int i = 0; i < cnt; i++, k++) {
            const int cc = k >> 6;
            if (cc != chunk) {                        // wave-uniform, once per 64 edges
                chunk = cc;
                const int rel = cc * 64 + lane;
                sv = esrc[(rel < ndeg) ? (o0 + rel) : o0];   // 1 coalesced load

                // cooperative alpha precompute: only the rounds that exist
                const int nval = min(64, ndeg - cc * 64);    // wave-uniform >0
                for (int s = 0; s < 4 && s * 16 < nval; s++) {
                    const int ein = s * 16 + esub;           // edge idx in chunk
                    float ww = 0.f;
                    if (ein < nval) {
                        const int sn = __shfl(sv, ein);
                        const int e  = cc * 64 + ein;
                        const int te = (e >= b0) + (e >= b1) + (e >= b2);
                        const float* ipp = si + ((size_t)te * N + node) * SSTRIDE + quad * 6;
                        const float* jpp = sj + ((size_t)te * N + sn)   * SSTRIDE + quad * 6;
                        const float2 i01 = *(const float2*)(ipp);
                        const float2 i23 = *(const float2*)(ipp + 2);
                        const float  i4  = ipp[4];
                        const float2 j01 = *(const float2*)(jpp);
                        const float2 j23 = *(const float2*)(jpp + 2);
                        const float  j4  = jpp[4];
                        float alpha = 0.f;
                        float s0 = i01.x + j01.x; s0 = (s0 > 0.f) ? s0 : 0.2f * s0; alpha += s0 * pk[0];
                        float s1 = i01.y + j01.y; s1 = (s1 > 0.f) ? s1 : 0.2f * s1; alpha += s1 * pk[1];
                        float s2 = i23.x + j23.x; s2 = (s2 > 0.f) ? s2 : 0.2f * s2; alpha += s2 * pk[2];
                        float s3 = i23.y + j23.y; s3 = (s3 > 0.f) ? s3 : 0.2f * s3; alpha += s3 * pk[3];
                        float s4 = i4    + j4;    s4 = (s4 > 0.f) ? s4 : 0.2f * s4; alpha += s4 * pk[4];
                        ww = __expf(alpha);
                    }
                    wrow[ein * 4 + quad] = ww;     // same-wave producer/consumer
                }
            }
            const int sn = __shfl(sv, k & 63);
            const float w = wrow[(k & 63) * 4 + quad];   // broadcast ds_read

            const unsigned u = ((const unsigned*)(tbase + (size_t)sn * D_OUT))[lane];
            ax  += __uint_as_float(u << 16) * w;
            ay  += __uint_as_float(u & 0xffff0000u) * w;
            den += w;
        }
        const float f = imp_s[t] / den;
        oacc0 += ax * f;
        oacc1 += ay * f;
    }

    // self-loop (type 0 transform of own features) + bias, pure store
    const unsigned u0 = ((const unsigned*)(xtb + (size_t)node * D_OUT))[lane];
    const float2 bv = ((const float2*)bias)[lane];
    float2 ov;
    ov.x = __uint_as_float(u0 << 16)          + bv.x + oacc0;
    ov.y = __uint_as_float(u0 & 0xffff0000u)  + bv.y + oacc1;
    ((float2*)(out + (size_t)node * D_OUT))[lane] = ov;
}

// ---------------------------------------------------------------------------
extern "C" void kernel_launch(void* const* d_in, const int* in_sizes, int n_in,
                              void* d_out, int out_size, void* d_ws, size_t ws_size,
                              hipStream_t stream) {
    const float* x    = (const float*)d_in[0];
    const int*   ei   = (const int*)d_in[1];
    const int*   et   = (const int*)d_in[2];
    const float* W    = (const float*)d_in[3];
    const float* attv = (const float*)d_in[4];
    const float* cpr  = (const float*)d_in[5];
    const float* imp  = (const float*)d_in[6];
    const float* bias = (const float*)d_in[7];

    const int N = in_sizes[0] / IN_CH;
    const int E = in_sizes[2];
    const int* src = ei;        // edge_index[0]
    const int* dst = ei + E;    // edge_index[1]
    const int NS = N * N_TYPES;

    char* ws = (char*)d_ws;
    float* si      = (float*)ws;  ws += (size_t)N_TYPES * N * SSTRIDE * sizeof(float);
    float* sj      = (float*)ws;  ws += (size_t)N_TYPES * N * SSTRIDE * sizeof(float);
    float* M       = (float*)ws;  ws += (size_t)N_TYPES * 128 * 48 * sizeof(float);
    short* Wth     = (short*)ws;  ws += (size_t)N_TYPES * DCOLS * 128 * sizeof(short);
    short* Wtl     = (short*)ws;  ws += (size_t)N_TYPES * DCOLS * 128 * sizeof(short);
    short* xtb     = (short*)ws;  ws += (size_t)N_TYPES * N * D_OUT * sizeof(short);
    int*   counts  = (int*)ws;    ws += (size_t)NS * sizeof(int);
    int*   offsets = (int*)ws;    ws += (size_t)NS * sizeof(int);
    int*   cursor  = (int*)ws;    ws += (size_t)NS * sizeof(int);
    int*   partial = (int*)ws;    ws += 256 * sizeof(int);
    int*   esrc    = (int*)ws;    ws += (size_t)E * sizeof(int);
    float* out = (float*)d_out;

    hipMemsetAsync(counts, 0, (size_t)NS * sizeof(int), stream);

    k_matt<<<(N_TYPES * 128 * 48 + 255) / 256, 256, 0, stream>>>(W, attv, M);
    k_wprep<<<(N_TYPES * 128 * DCOLS + 255) / 256, 256, 0, stream>>>(W, M, Wth, Wtl);

    const int nblocks = (N + 63) / 64;
    k_linear<<<dim3(nblocks, N_TYPES), 256, 0, stream>>>(x, Wth, Wtl, xtb, si, sj, N);

    const int eb = (E + 255) / 256;
    const int nb = (NS + 1023) / 1024;
    k_hist<<<eb, 256, 0, stream>>>(dst, et, counts, E);
    k_scan_part<<<nb, 256, 0, stream>>>(counts, partial, NS);
    k_scan_partials<<<1, 256, 0, stream>>>(partial, nb);
    k_scan_chunk<<<nb, 256, 0, stream>>>(counts, partial, offsets, cursor, NS);
    k_fill<<<eb, 256, 0, stream>>>(src, dst, et, cursor, esrc, E);

    k_node<<<(N + 3) / 4, 256, 0, stream>>>(xtb, offsets, counts, esrc, si, sj, cpr, imp, bias, out, N);
}

// Round 6
// 308.404 us; speedup vs baseline: 1.1594x; 1.0583x over previous
//
#include <hip/hip_runtime.h>

#define IN_CH   128
#define D_OUT   128   // OUT_CH*HEADS
#define HEADS   4
#define N_TYPES 4
#define N_CONF  5
#define DCOLS   192   // 128 xt cols + 48 score cols (40 real + 8 pad)
#define SSTRIDE 24    // si/sj per-row stride: h*6+q (q<5 used)

typedef __attribute__((ext_vector_type(8))) short bf16x8;   // 8 bf16 (4 VGPRs)
typedef __attribute__((ext_vector_type(4))) float f32x4;

__device__ inline unsigned short bf16_rne(float f) {
    unsigned u = __float_as_uint(f);
    u += 0x7fff + ((u >> 16) & 1);
    return (unsigned short)(u >> 16);
}
// hi/lo split: f ~= hi + lo with ~2^-16 relative residual
__device__ inline void split_hl(float f, short& h, short& l) {
    unsigned u = __float_as_uint(f);
    h = (short)(u >> 16);
    float r = f - __uint_as_float(u & 0xffff0000u);   // exact
    l = (short)(__float_as_uint(r) >> 16);
}

// per-edge attention weight: SAME fp op order as all passing rounds
__device__ __forceinline__ float edge_w(const float* __restrict__ si,
                                        const float* __restrict__ sj,
                                        int te, int node, int eidx, int quad, int N,
                                        float pk0, float pk1, float pk2, float pk3, float pk4) {
    const float* ipp = si + ((size_t)te * N + node) * SSTRIDE + quad * 6;
    const float* jpp = sj + (size_t)eidx * SSTRIDE + quad * 6;   // eidx = te*N + sn
    const float2 i01 = *(const float2*)(ipp);
    const float2 i23 = *(const float2*)(ipp + 2);
    const float  i4  = ipp[4];
    const float2 j01 = *(const float2*)(jpp);
    const float2 j23 = *(const float2*)(jpp + 2);
    const float  j4  = jpp[4];
    float alpha = 0.f;
    float s0 = i01.x + j01.x; s0 = (s0 > 0.f) ? s0 : 0.2f * s0; alpha += s0 * pk0;
    float s1 = i01.y + j01.y; s1 = (s1 > 0.f) ? s1 : 0.2f * s1; alpha += s1 * pk1;
    float s2 = i23.x + j23.x; s2 = (s2 > 0.f) ? s2 : 0.2f * s2; alpha += s2 * pk2;
    float s3 = i23.y + j23.y; s3 = (s3 > 0.f) ? s3 : 0.2f * s3; alpha += s3 * pk3;
    float s4 = i4    + j4;    s4 = (s4 > 0.f) ? s4 : 0.2f * s4; alpha += s4 * pk4;
    return __expf(alpha);
}

// ---------------------------------------------------------------------------
// k_matt: M[t][k][col] = sum_{d'<32} W[t][k][32h+d'] * attv[q][h][fb*32+d']
// ---------------------------------------------------------------------------
__global__ __launch_bounds__(256) void k_matt(const float* __restrict__ W,
                                              const float* __restrict__ attv,
                                              float* __restrict__ M) {
    const int g = blockIdx.x * 256 + threadIdx.x;   // 4*128*48
    if (g >= N_TYPES * 128 * 48) return;
    const int col = g % 48;
    const int k   = (g / 48) % 128;
    const int t   = g / (48 * 128);
    const int fb  = col / 24;
    const int rem = col % 24;
    const int h   = rem / 6;
    const int q   = rem % 6;
    float acc = 0.f;
    if (q < N_CONF) {
        const float* wr = W + ((size_t)t * 128 + k) * 128 + 32 * h;
        const float* ar = attv + ((size_t)q * HEADS + h) * 64 + fb * 32;
#pragma unroll
        for (int d = 0; d < 32; d++) acc += wr[d] * ar[d];
    }
    M[g] = acc;
}

// ---------------------------------------------------------------------------
// k_wprep: Wth/Wtl[t][dcol][k] = hi/lo bf16 of B'[t][k][dcol]
// ---------------------------------------------------------------------------
__global__ __launch_bounds__(256) void k_wprep(const float* __restrict__ W,
                                               const float* __restrict__ M,
                                               short* __restrict__ Wth,
                                               short* __restrict__ Wtl) {
    const int g = blockIdx.x * 256 + threadIdx.x;   // 4*128*192, dcol fastest
    if (g >= N_TYPES * 128 * DCOLS) return;
    const int dcol = g % DCOLS;
    const int k    = (g / DCOLS) % 128;
    const int t    = g / (DCOLS * 128);
    float v = 0.f;
    if (dcol < 128)      v = W[((size_t)t * 128 + k) * 128 + dcol];
    else if (dcol < 176) v = M[((size_t)t * 128 + k) * 48 + (dcol - 128)];
    short h, l; split_hl(v, h, l);
    const size_t o = ((size_t)t * DCOLS + dcol) * 128 + k;
    Wth[o] = h; Wtl[o] = l;
}

// ---------------------------------------------------------------------------
// k_linear (v0, proven 70us): bf16 hi/lo MFMA GEMM, [64 x 128] x [128 x 192].
// ---------------------------------------------------------------------------
__global__ __launch_bounds__(256) void k_linear(const float* __restrict__ x,
                                                const short* __restrict__ Wth,
                                                const short* __restrict__ Wtl,
                                                short* __restrict__ xtb,
                                                float* __restrict__ si,
                                                float* __restrict__ sj,
                                                int N) {
    __shared__ __align__(16) char smem[34816];
    short* Xh = (short*)smem;             // 64*136 shorts
    short* Xl = (short*)(smem + 17408);   // 64*136 shorts

    const int tid   = threadIdx.x;
    const int nbase = blockIdx.x * 64;
    const int t     = blockIdx.y;

    // stage X tile -> hi/lo bf16
#pragma unroll
    for (int i = 0; i < 8; i++) {
        const int f   = tid + i * 256;       // 0..2047
        const int row = f >> 5;
        const int c4  = (f & 31) * 4;
        float4 v = make_float4(0.f, 0.f, 0.f, 0.f);
        const int ng = nbase + row;
        if (ng < N) v = *(const float4*)(x + (size_t)ng * IN_CH + c4);
        short4 h4, l4;
        split_hl(v.x, h4.x, l4.x);
        split_hl(v.y, h4.y, l4.y);
        split_hl(v.z, h4.z, l4.z);
        split_hl(v.w, h4.w, l4.w);
        *(short4*)(Xh + row * 136 + c4) = h4;
        *(short4*)(Xl + row * 136 + c4) = l4;
    }
    __syncthreads();

    const int w    = tid >> 6;
    const int lane = tid & 63;
    const int n16  = lane & 15;
    const int quad = lane >> 4;

    f32x4 acc[3][4];
#pragma unroll
    for (int tt = 0; tt < 3; tt++)
#pragma unroll
        for (int mt = 0; mt < 4; mt++) acc[tt][mt] = (f32x4){0.f, 0.f, 0.f, 0.f};

#pragma unroll
    for (int kc = 0; kc < 4; kc++) {
        bf16x8 Ah[4], Al[4];
#pragma unroll
        for (int mt = 0; mt < 4; mt++) {
            const int r = (mt * 16 + n16) * 136 + kc * 32 + quad * 8;
            Ah[mt] = *(const bf16x8*)(Xh + r);
            Al[mt] = *(const bf16x8*)(Xl + r);
        }
#pragma unroll
        for (int tt = 0; tt < 3; tt++) {
            const int dcol = (w * 3 + tt) * 16 + n16;
            const size_t off = ((size_t)t * DCOLS + dcol) * 128 + kc * 32 + quad * 8;
            const bf16x8 Bh = *(const bf16x8*)(Wth + off);
            const bf16x8 Bl = *(const bf16x8*)(Wtl + off);
#pragma unroll
            for (int mt = 0; mt < 4; mt++) {
                acc[tt][mt] = __builtin_amdgcn_mfma_f32_16x16x32_bf16(Ah[mt], Bh, acc[tt][mt], 0, 0, 0);
                acc[tt][mt] = __builtin_amdgcn_mfma_f32_16x16x32_bf16(Ah[mt], Bl, acc[tt][mt], 0, 0, 0);
                acc[tt][mt] = __builtin_amdgcn_mfma_f32_16x16x32_bf16(Al[mt], Bh, acc[tt][mt], 0, 0, 0);
            }
        }
    }

    // -------- stage epilogue through LDS (reuse smem) --------
    __syncthreads();
    unsigned short* SB = (unsigned short*)smem;     // [64][128], 16B-block swizzled
    float*          SS = (float*)(smem + 16384);    // [64][48]

#pragma unroll
    for (int tt = 0; tt < 3; tt++) {
        const int dcol = (w * 3 + tt) * 16 + n16;
        if (dcol < 128) {
            const int blk = dcol >> 3;
#pragma unroll
            for (int mt = 0; mt < 4; mt++)
#pragma unroll
                for (int r = 0; r < 4; r++) {
                    const int nl = mt * 16 + quad * 4 + r;
                    SB[nl * 128 + (((blk ^ (nl & 15)) << 3) | (dcol & 7))] =
                        bf16_rne(acc[tt][mt][r]);
                }
        } else if (dcol < 176) {
            const int c = dcol - 128;   // 0..47: [si 0..23 | sj 0..23]
#pragma unroll
            for (int mt = 0; mt < 4; mt++)
#pragma unroll
                for (int r = 0; r < 4; r++) {
                    const int nl = mt * 16 + quad * 4 + r;
                    SS[nl * 48 + c] = acc[tt][mt][r];
                }
        }
    }
    __syncthreads();

    const size_t trow = (size_t)t * N;
#pragma unroll
    for (int it = 0; it < 4; it++) {
        const int task = tid + it * 256;        // 0..1023
        const int r    = task >> 4;
        const int blk  = task & 15;
        if (nbase + r < N) {
            const uint4 v = *(const uint4*)(SB + r * 128 + ((blk ^ (r & 15)) << 3));
            *(uint4*)(xtb + (trow + nbase + r) * (size_t)D_OUT + (blk << 3)) = v;
        }
    }
#pragma unroll
    for (int it = 0; it < 3; it++) {
        const int task = tid + it * 256;        // 0..767
        const int r    = task / 12;
        const int p    = task % 12;
        if (nbase + r < N) {
            const float4 v = *(const float4*)(SS + r * 48 + p * 4);
            float* dp = (p < 6) ? (si + (trow + nbase + r) * SSTRIDE + p * 4)
                                : (sj + (trow + nbase + r) * SSTRIDE + (p - 6) * 4);
            *(float4*)dp = v;
        }
    }
}

// ---------------------------------------------------------------------------
// CSR build over segments seg = dst*4 + type
// ---------------------------------------------------------------------------
__global__ __launch_bounds__(256) void k_hist(const int* __restrict__ dst,
                                              const int* __restrict__ et,
                                              int* __restrict__ counts, int E) {
    const int e = blockIdx.x * 256 + threadIdx.x;
    if (e < E) atomicAdd(&counts[dst[e] * 4 + et[e]], 1);
}

__global__ __launch_bounds__(256) void k_scan_part(const int* __restrict__ counts,
                                                   int* __restrict__ partial, int NS) {
    __shared__ int s[256];
    const int b = blockIdx.x, t = threadIdx.x;
    const int base = b * 1024 + t * 4;
    int sum = 0;
#pragma unroll
    for (int i = 0; i < 4; i++) if (base + i < NS) sum += counts[base + i];
    s[t] = sum; __syncthreads();
    for (int off = 128; off > 0; off >>= 1) {
        if (t < off) s[t] += s[t + off];
        __syncthreads();
    }
    if (t == 0) partial[b] = s[0];
}

__global__ __launch_bounds__(256) void k_scan_partials(int* __restrict__ partial, int nb) {
    __shared__ int s[256];
    const int t = threadIdx.x;
    int v = (t < nb) ? partial[t] : 0;
    s[t] = v; __syncthreads();
    for (int off = 1; off < 256; off <<= 1) {
        int x = (t >= off) ? s[t - off] : 0;
        __syncthreads();
        s[t] += x;
        __syncthreads();
    }
    if (t < nb) partial[t] = s[t] - v;   // exclusive
}

__global__ __launch_bounds__(256) void k_scan_chunk(const int* __restrict__ counts,
                                                    const int* __restrict__ partial,
                                                    int* __restrict__ offsets,
                                                    int* __restrict__ cursor, int NS) {
    __shared__ int s[256];
    const int b = blockIdx.x, t = threadIdx.x;
    const int base = b * 1024 + t * 4;
    int v[4]; int sum = 0;
#pragma unroll
    for (int i = 0; i < 4; i++) { v[i] = (base + i < NS) ? counts[base + i] : 0; sum += v[i]; }
    s[t] = sum; __syncthreads();
    for (int off = 1; off < 256; off <<= 1) {
        int x = (t >= off) ? s[t - off] : 0;
        __syncthreads();
        s[t] += x;
        __syncthreads();
    }
    int run = partial[b] + s[t] - sum;
#pragma unroll
    for (int i = 0; i < 4; i++) {
        const int idx = base + i;
        if (idx < NS) { offsets[idx] = run; cursor[idx] = run; run += v[i]; }
    }
}

// k_fill: only esrc (type derived from CSR walk)
__global__ __launch_bounds__(256) void k_fill(const int* __restrict__ src,
                                              const int* __restrict__ dst,
                                              const int* __restrict__ et,
                                              int* __restrict__ cursor,
                                              int* __restrict__ esrc, int E) {
    const int e = blockIdx.x * 256 + threadIdx.x;
    if (e < E) {
        const int seg = dst[e] * 4 + et[e];
        const int pos = atomicAdd(&cursor[seg], 1);
        esrc[pos] = src[e];
    }
}

// ---------------------------------------------------------------------------
// k_node v4: one wave per dst node. Changes vs v3:
//  - type folded into CSR index (idx = te*N + sn) at chunk load -> ONE flat
//    edge loop, no per-type ax/ay/den epilogue, no per-edge den add;
//  - normalization folded into LDS weight (w * imp_t/den_t), den via 4-step
//    shfl_xor quad reduce over the cooperative precompute registers;
//  - inner loop 2-wide unrolled (2 gathers in flight, pairs never straddle
//    64-edge chunks) with readlane (SGPR broadcast + saddr load) replacing
//    the per-edge ds_bpermute.
// ---------------------------------------------------------------------------
__global__ __launch_bounds__(256) void k_node(const short* __restrict__ xtb,
                                              const int* __restrict__ offsets,
                                              const int* __restrict__ counts,
                                              const int* __restrict__ esrc,
                                              const float* __restrict__ si,
                                              const float* __restrict__ sj,
                                              const float* __restrict__ cprobs,
                                              const float* __restrict__ imp,
                                              const float* __restrict__ bias,
                                              float* __restrict__ out,
                                              int N) {
    __shared__ float imp_s[N_TYPES];
    __shared__ float pk_s[N_CONF];
    __shared__ float wlds[4][64 * HEADS];   // per-wave weight table [edge][head]
    if (threadIdx.x == 0) {
        float m = cprobs[0];
        for (int k = 1; k < N_CONF; k++) m = fmaxf(m, cprobs[k]);
        float ex[N_CONF], s = 0.f;
        for (int k = 0; k < N_CONF; k++) { ex[k] = __expf(cprobs[k] - m); s += ex[k]; }
        for (int k = 0; k < N_CONF; k++) pk_s[k] = ex[k] / s;
    }
    if (threadIdx.x < N_TYPES) imp_s[threadIdx.x] = imp[threadIdx.x];
    __syncthreads();

    const float pk0 = pk_s[0], pk1 = pk_s[1], pk2 = pk_s[2], pk3 = pk_s[3], pk4 = pk_s[4];
    const float im0 = imp_s[0], im1 = imp_s[1], im2 = imp_s[2], im3 = imp_s[3];

    const int wid  = threadIdx.x >> 6;
    const int node = blockIdx.x * 4 + wid;
    if (node >= N) return;
    const int lane = threadIdx.x & 63;
    const int quad = lane >> 4;   // head
    const int esub = lane & 15;
    float* wrow = wlds[wid];

    const int o0 = offsets[node * 4];
    int c[N_TYPES];
#pragma unroll
    for (int t = 0; t < N_TYPES; t++) c[t] = counts[node * 4 + t];
    const int ndeg = c[0] + c[1] + c[2] + c[3];
    const int b0 = c[0];
    const int b1 = c[0] + c[1];
    const int b2 = b1 + c[2];

    float oacc0 = 0.f, oacc1 = 0.f;

    if (ndeg > 0) {
        const int nchunks = (ndeg + 63) >> 6;

        // ---- rare multi-chunk (deg > 64): global den pre-pass ----
        float gden0 = 0.f, gden1 = 0.f, gden2 = 0.f, gden3 = 0.f;
        if (nchunks > 1) {
            for (int cc = 0; cc < nchunks; cc++) {
                const int ebase = cc * 64;
                const int nval  = min(64, ndeg - ebase);
                const int rel   = ebase + lane;
                const int sn    = esrc[(rel < ndeg) ? (o0 + rel) : o0];
                const int tel   = (rel >= b0) + (rel >= b1) + (rel >= b2);
                const int idx   = tel * N + sn;
#pragma unroll
                for (int s = 0; s < 4; s++) {
                    if (s * 16 < nval) {
                        const int ein = s * 16 + esub;
                        if (ein < nval) {
                            const int eidx = __shfl(idx, ein);
                            const int e    = ebase + ein;
                            const int te   = (e >= b0) + (e >= b1) + (e >= b2);
                            const float ww = edge_w(si, sj, te, node, eidx, quad, N,
                                                    pk0, pk1, pk2, pk3, pk4);
                            gden0 += (te == 0) ? ww : 0.f;
                            gden1 += (te == 1) ? ww : 0.f;
                            gden2 += (te == 2) ? ww : 0.f;
                            gden3 += (te == 3) ? ww : 0.f;
                        }
                    }
                }
            }
#pragma unroll
            for (int m = 1; m < 16; m <<= 1) {
                gden0 += __shfl_xor(gden0, m);
                gden1 += __shfl_xor(gden1, m);
                gden2 += __shfl_xor(gden2, m);
                gden3 += __shfl_xor(gden3, m);
            }
        }

        // ---- main per-chunk: weights -> den -> scale -> flat gather loop ----
        for (int cc = 0; cc < nchunks; cc++) {
            const int ebase = cc * 64;
            const int nval  = min(64, ndeg - ebase);
            const int rel   = ebase + lane;
            const int sn    = esrc[(rel < ndeg) ? (o0 + rel) : o0];
            const int tel   = (rel >= b0) + (rel >= b1) + (rel >= b2);
            const int idx   = tel * N + sn;     // te*N+sn; invalid lanes never consumed

            // cooperative weights: lane (quad, esub) -> head=quad, edge=s*16+esub
            float ww0 = 0.f, ww1 = 0.f, ww2 = 0.f, ww3 = 0.f;
            float d0 = 0.f, d1 = 0.f, d2 = 0.f, d3 = 0.f;
#pragma unroll
            for (int s = 0; s < 4; s++) {
                if (s * 16 < nval) {
                    const int ein = s * 16 + esub;
                    if (ein < nval) {
                        const int eidx = __shfl(idx, ein);
                        const int e    = ebase + ein;
                        const int te   = (e >= b0) + (e >= b1) + (e >= b2);
                        const float ww = edge_w(si, sj, te, node, eidx, quad, N,
                                                pk0, pk1, pk2, pk3, pk4);
                        if (s == 0) ww0 = ww; else if (s == 1) ww1 = ww;
                        else if (s == 2) ww2 = ww; else ww3 = ww;
                        d0 += (te == 0) ? ww : 0.f;
                        d1 += (te == 1) ? ww : 0.f;
                        d2 += (te == 2) ? ww : 0.f;
                        d3 += (te == 3) ? ww : 0.f;
                    }
                }
            }

            float den0, den1, den2, den3;
            if (nchunks == 1) {
#pragma unroll
                for (int m = 1; m < 16; m <<= 1) {
                    d0 += __shfl_xor(d0, m);
                    d1 += __shfl_xor(d1, m);
                    d2 += __shfl_xor(d2, m);
                    d3 += __shfl_xor(d3, m);
                }
                den0 = d0; den1 = d1; den2 = d2; den3 = d3;
            } else {
                den0 = gden0; den1 = gden1; den2 = gden2; den3 = gden3;
            }

            // scale + park in LDS (slots >= nval never read)
#pragma unroll
            for (int s = 0; s < 4; s++) {
                if (s * 16 < nval) {
                    const int ein = s * 16 + esub;
                    const int e   = ebase + ein;
                    const int te  = (e >= b0) + (e >= b1) + (e >= b2);
                    const float dn = (te == 0) ? den0 : ((te == 1) ? den1 : ((te == 2) ? den2 : den3));
                    const float im = (te == 0) ? im0  : ((te == 1) ? im1  : ((te == 2) ? im2  : im3));
                    const float ww = (s == 0) ? ww0 : ((s == 1) ? ww1 : ((s == 2) ? ww2 : ww3));
                    wrow[ein * 4 + quad] = ww * (im / dn);
                }
            }

            // flat 2-wide gather loop: 2 independent saddr loads in flight
            int kk = 0;
            for (; kk + 1 < nval; kk += 2) {
                const int i0 = __builtin_amdgcn_readlane(idx, kk);
                const int i1 = __builtin_amdgcn_readlane(idx, kk + 1);
                const float w0 = wrow[kk * 4 + quad];
                const float w1 = wrow[(kk + 1) * 4 + quad];
                const unsigned u0 = ((const unsigned*)(xtb + (size_t)i0 * D_OUT))[lane];
                const unsigned u1 = ((const unsigned*)(xtb + (size_t)i1 * D_OUT))[lane];
                oacc0 += __uint_as_float(u0 << 16) * w0;
                oacc1 += __uint_as_float(u0 & 0xffff0000u) * w0;
                oacc0 += __uint_as_float(u1 << 16) * w1;
                oacc1 += __uint_as_float(u1 & 0xffff0000u) * w1;
            }
            if (kk < nval) {
                const int i0 = __builtin_amdgcn_readlane(idx, kk);
                const float w0 = wrow[kk * 4 + quad];
                const unsigned u0 = ((const unsigned*)(xtb + (size_t)i0 * D_OUT))[lane];
                oacc0 += __uint_as_float(u0 << 16) * w0;
                oacc1 += __uint_as_float(u0 & 0xffff0000u) * w0;
            }
        }
    }

    // self-loop (type 0 transform of own features) + bias, pure store
    const unsigned u0 = ((const unsigned*)(xtb + (size_t)node * D_OUT))[lane];
    const float2 bv = ((const float2*)bias)[lane];
    float2 ov;
    ov.x = __uint_as_float(u0 << 16)          + bv.x + oacc0;
    ov.y = __uint_as_float(u0 & 0xffff0000u)  + bv.y + oacc1;
    ((float2*)(out + (size_t)node * D_OUT))[lane] = ov;
}

// ---------------------------------------------------------------------------
extern "C" void kernel_launch(void* const* d_in, const int* in_sizes, int n_in,
                              void* d_out, int out_size, void* d_ws, size_t ws_size,
                              hipStream_t stream) {
    const float* x    = (const float*)d_in[0];
    const int*   ei   = (const int*)d_in[1];
    const int*   et   = (const int*)d_in[2];
    const float* W    = (const float*)d_in[3];
    const float* attv = (const float*)d_in[4];
    const float* cpr  = (const float*)d_in[5];
    const float* imp  = (const float*)d_in[6];
    const float* bias = (const float*)d_in[7];

    const int N = in_sizes[0] / IN_CH;
    const int E = in_sizes[2];
    const int* src = ei;        // edge_index[0]
    const int* dst = ei + E;    // edge_index[1]
    const int NS = N * N_TYPES;

    char* ws = (char*)d_ws;
    float* si      = (float*)ws;  ws += (size_t)N_TYPES * N * SSTRIDE * sizeof(float);
    float* sj      = (float*)ws;  ws += (size_t)N_TYPES * N * SSTRIDE * sizeof(float);
    float* M       = (float*)ws;  ws += (size_t)N_TYPES * 128 * 48 * sizeof(float);
    short* Wth     = (short*)ws;  ws += (size_t)N_TYPES * DCOLS * 128 * sizeof(short);
    short* Wtl     = (short*)ws;  ws += (size_t)N_TYPES * DCOLS * 128 * sizeof(short);
    short* xtb     = (short*)ws;  ws += (size_t)N_TYPES * N * D_OUT * sizeof(short);
    int*   counts  = (int*)ws;    ws += (size_t)NS * sizeof(int);
    int*   offsets = (int*)ws;    ws += (size_t)NS * sizeof(int);
    int*   cursor  = (int*)ws;    ws += (size_t)NS * sizeof(int);
    int*   partial = (int*)ws;    ws += 256 * sizeof(int);
    int*   esrc    = (int*)ws;    ws += (size_t)E * sizeof(int);
    float* out = (float*)d_out;

    hipMemsetAsync(counts, 0, (size_t)NS * sizeof(int), stream);

    k_matt<<<(N_TYPES * 128 * 48 + 255) / 256, 256, 0, stream>>>(W, attv, M);
    k_wprep<<<(N_TYPES * 128 * DCOLS + 255) / 256, 256, 0, stream>>>(W, M, Wth, Wtl);

    const int nblocks = (N + 63) / 64;
    k_linear<<<dim3(nblocks, N_TYPES), 256, 0, stream>>>(x, Wth, Wtl, xtb, si, sj, N);

    const int eb = (E + 255) / 256;
    const int nb = (NS + 1023) / 1024;
    k_hist<<<eb, 256, 0, stream>>>(dst, et, counts, E);
    k_scan_part<<<nb, 256, 0, stream>>>(counts, partial, NS);
    k_scan_partials<<<1, 256, 0, stream>>>(partial, nb);
    k_scan_chunk<<<nb, 256, 0, stream>>>(counts, partial, offsets, cursor, NS);
    k_fill<<<eb, 256, 0, stream>>>(src, dst, et, cursor, esrc, E);

    k_node<<<(N + 3) / 4, 256, 0, stream>>>(xtb, offsets, counts, esrc, si, sj, cpr, imp, bias, out, N);
}